// Round 1
// baseline (1179.279 us; speedup 1.0000x reference)
//
#include <hip/hip_runtime.h>
#include <cstdint>

#define B_ 64
#define N_ 512
#define D_ 256
#define L_ 4

typedef __bf16 bf16;
typedef __attribute__((ext_vector_type(8))) __bf16 bf16x8;
typedef __attribute__((ext_vector_type(4))) __bf16 bf16x4;
typedef __attribute__((ext_vector_type(4))) float f32x4;

__device__ __forceinline__ void async_copy16(void* lds, const void* glb) {
  __builtin_amdgcn_global_load_lds(
      (const __attribute__((address_space(1))) void*)glb,
      (__attribute__((address_space(3))) void*)lds, 16, 0, 0);
}

__device__ __forceinline__ float sigmoidf_(float z) {
  return 1.0f / (1.0f + __expf(-z));
}

// ---------------------------------------------------------------------------
// Generic bf16 GEMM:  C[m][n] = sum_k A[m][k] * Bm[n][k]   (i.e. A * Bm^T)
// A row-major MxK (lda), Bm row-major Nout x K (ldb). Tiles: BM=BN=128, BK=32.
// 256 threads = 4 waves, each wave computes a 64x64 quadrant as 4x4 MFMA tiles.
// Epilogue: +bias[n], optional relu, optional +resid (f32), stores to any of
// outF (f32), outB (bf16), outT (bf16 transposed [b][d][n], lin1 only).
// grid = (Nout/128, M/128, nbatch)
// ---------------------------------------------------------------------------
__global__ __launch_bounds__(256, 2) void gemm_bt(
    const bf16* __restrict__ A, const bf16* __restrict__ Bm,
    const float* __restrict__ bias, const float* __restrict__ resid,
    float* __restrict__ outF, bf16* __restrict__ outB, bf16* __restrict__ outT,
    int M, int K, int lda, int ldb, int ldc,
    long long sA, long long sB, long long sC, int relu)
{
  __shared__ bf16 As[128 * 32];
  __shared__ bf16 Bs[128 * 32];
  const int tid = threadIdx.x;
  const int w = tid >> 6, lane = tid & 63;
  const int l16 = lane & 15, quad = lane >> 4;
  const int wm = w & 1, wn = w >> 1;
  const int bx = blockIdx.x, by = blockIdx.y, bz = blockIdx.z;
  A  += (size_t)bz * sA;
  Bm += (size_t)bz * sB;
  const size_t cofs = (size_t)bz * sC;

  f32x4 acc[4][4] = {};

  // staging: 8 chunks of 1024B per tile; wave w stages chunks {w, w+4}.
  // XOR swizzle of 16B granules by (row>>1)&3 to spread LDS banks.
  const int arow = lane >> 2;                        // row within 16-row chunk
  const int acg  = (lane & 3) ^ ((lane >> 3) & 3);   // swizzled source granule
  const int sw   = (quad ^ ((l16 >> 1) & 3)) << 3;   // frag-read elem offset

  const int nk = K >> 5;
  for (int kc = 0; kc < nk; ++kc) {
    const int k0 = kc << 5;
#pragma unroll
    for (int r = 0; r < 2; ++r) {
      const int c = w + (r << 2);
      const int row = (c << 4) + arow;
      async_copy16(&As[c * 512],
                   A + (size_t)(by * 128 + row) * lda + k0 + (acg << 3));
      async_copy16(&Bs[c * 512],
                   Bm + (size_t)(bx * 128 + row) * ldb + k0 + (acg << 3));
    }
    __syncthreads();
    bf16x8 af[4], bfv[4];
#pragma unroll
    for (int i = 0; i < 4; ++i) {
      af[i]  = *(const bf16x8*)&As[(wm * 64 + i * 16 + l16) * 32 + sw];
      bfv[i] = *(const bf16x8*)&Bs[(wn * 64 + i * 16 + l16) * 32 + sw];
    }
#pragma unroll
    for (int i = 0; i < 4; ++i)
#pragma unroll
      for (int j = 0; j < 4; ++j)
        acc[i][j] = __builtin_amdgcn_mfma_f32_16x16x32_bf16(af[i], bfv[j],
                                                            acc[i][j], 0, 0, 0);
    __syncthreads();
  }

  // epilogue: C layout col = lane&15, row = quad*4 + reg
  const int rbase = by * 128 + wm * 64 + (quad << 2);
  const int cbase = bx * 128 + wn * 64 + l16;
#pragma unroll
  for (int j = 0; j < 4; ++j) {
    const int col = cbase + j * 16;
    const float bv = bias ? bias[col] : 0.0f;
#pragma unroll
    for (int i = 0; i < 4; ++i) {
      const int r0 = rbase + i * 16;
      float v[4];
#pragma unroll
      for (int r = 0; r < 4; ++r) {
        float t = acc[i][j][r] + bv;
        if (relu) t = fmaxf(t, 0.0f);
        if (resid) t += resid[cofs + (size_t)(r0 + r) * ldc + col];
        v[r] = t;
      }
      if (outF) {
#pragma unroll
        for (int r = 0; r < 4; ++r)
          outF[cofs + (size_t)(r0 + r) * ldc + col] = v[r];
      }
      if (outB) {
#pragma unroll
        for (int r = 0; r < 4; ++r)
          outB[cofs + (size_t)(r0 + r) * ldc + col] = (bf16)v[r];
      }
      if (outT) {  // xT[b][d=col][node]; 4 consecutive nodes -> one 8B store
        bf16x4 tv;
#pragma unroll
        for (int r = 0; r < 4; ++r) tv[r] = (bf16)v[r];
        *(bf16x4*)&outT[((size_t)(r0 >> 9)) * (D_ * N_) + (size_t)col * N_ +
                        (r0 & (N_ - 1))] = tv;
      }
    }
  }
}

// ---------------------------------------------------------------------------
// Fused attention: for a 16-row tile of one batch:
//   S = sigmoid(q_tile @ x_b^T); S = (S + 1e-5*I) * adj(diag=1);
//   S /= rowsum(S);  write S to out_attn (f32) and Sb (bf16).
// grid = (N/16, B), 256 threads = 4 waves; wave w covers col tiles w*8..w*8+7.
// ---------------------------------------------------------------------------
__global__ __launch_bounds__(256, 2) void attn_kernel(
    const bf16* __restrict__ q, const bf16* __restrict__ xb,
    const float* __restrict__ adj, float* __restrict__ outA,
    bf16* __restrict__ Sb)
{
  __shared__ bf16 qs[16 * 264];     // padded stride 264 (2-way max conflicts)
  __shared__ float Sl[16 * 516];    // padded stride 516
  __shared__ float psum[16 * 16];
  __shared__ float rinv[16];
  const int tid = threadIdx.x, w = tid >> 6, lane = tid & 63;
  const int l16 = lane & 15, quad = lane >> 4;
  const int rt = blockIdx.x, b = blockIdx.y;
  const int row0 = rt * 16;

  // load q tile [16][256] bf16 into LDS (coalesced 16B per thread, x2)
#pragma unroll
  for (int e = 0; e < 2; ++e) {
    const int cc = tid + e * 256;      // 8-element chunk id
    const int r = cc >> 5, cg = cc & 31;
    bf16x8 v = *(const bf16x8*)(q + ((size_t)(b * N_ + row0 + r)) * D_ + cg * 8);
    *(bf16x8*)&qs[r * 264 + cg * 8] = v;
  }
  __syncthreads();

  f32x4 acc[8] = {};
  const bf16* xrow[8];
#pragma unroll
  for (int t = 0; t < 8; ++t)
    xrow[t] = xb + ((size_t)(b * N_ + (w * 8 + t) * 16 + l16)) * D_ + quad * 8;

  for (int ks = 0; ks < 8; ++ks) {
    const bf16x8 af = *(const bf16x8*)&qs[l16 * 264 + ks * 32 + quad * 8];
    bf16x8 bb[8];
#pragma unroll
    for (int t = 0; t < 8; ++t)
      bb[t] = *(const bf16x8*)(xrow[t] + ks * 32);
#pragma unroll
    for (int t = 0; t < 8; ++t)
      acc[t] = __builtin_amdgcn_mfma_f32_16x16x32_bf16(af, bb[t], acc[t], 0, 0, 0);
  }

  // epilogue: sigmoid, diag, adjacency mask -> Sl
#pragma unroll
  for (int t = 0; t < 8; ++t) {
    const int gcol = (w * 8 + t) * 16 + l16;
#pragma unroll
    for (int r = 0; r < 4; ++r) {
      const int lrow = (quad << 2) + r;
      const int grow = row0 + lrow;
      float sg = sigmoidf_(acc[t][r]);
      float av;
      if (grow == gcol) { sg += 1e-5f; av = 1.0f; }
      else              { av = adj[((size_t)b * N_ + grow) * N_ + gcol]; }
      Sl[lrow * 516 + gcol] = sg * av;
    }
  }
  __syncthreads();

  // row sums: 16 threads/row, 32 elems each, then 16-wide reduce
  {
    const int rr = tid >> 4, seg = tid & 15;
    float p = 0.f;
#pragma unroll
    for (int k = 0; k < 32; ++k) p += Sl[rr * 516 + seg + k * 16];
    psum[rr * 16 + seg] = p;
  }
  __syncthreads();
  if (tid < 16) {
    float s = 0.f;
#pragma unroll
    for (int k = 0; k < 16; ++k) s += psum[tid * 16 + k];
    rinv[tid] = 1.0f / s;
  }
  __syncthreads();

  // normalize + store (coalesced)
  const size_t obase = ((size_t)b * N_ + row0) * N_;
  for (int idx = tid; idx < 16 * N_; idx += 256) {
    const int rr = idx >> 9, cc = idx & (N_ - 1);
    const float v = Sl[rr * 516 + cc] * rinv[rr];
    outA[obase + (size_t)rr * N_ + cc] = v;
    Sb[obase + (size_t)rr * N_ + cc] = (bf16)v;
  }
}

// ---------------------------------------------------------------------------
// init: copy x -> out_x (f32 master), x_bf16, and xT_bf16 (LDS 32x32 transpose)
// grid = (N/32, D/32, B), 256 threads
// ---------------------------------------------------------------------------
__global__ __launch_bounds__(256) void init_x(
    const float* __restrict__ x, float* __restrict__ outX,
    bf16* __restrict__ xb, bf16* __restrict__ xT)
{
  __shared__ float t[32 * 33];
  const int tid = threadIdx.x;
  const int nt = blockIdx.x, dt = blockIdx.y, b = blockIdx.z;
#pragma unroll
  for (int e = 0; e < 4; ++e) {
    const int idx = tid + e * 256;
    const int r = idx >> 5, c = idx & 31;
    const size_t g = ((size_t)(b * N_ + nt * 32 + r)) * D_ + dt * 32 + c;
    const float v = x[g];
    outX[g] = v;
    xb[g] = (bf16)v;
    t[r * 33 + c] = v;
  }
  __syncthreads();
#pragma unroll
  for (int e = 0; e < 4; ++e) {
    const int idx = tid + e * 256;
    const int r = idx >> 5, c = idx & 31;  // r: d-within-tile, c: n-within-tile
    xT[((size_t)(b * D_ + dt * 32 + r)) * N_ + nt * 32 + c] = (bf16)t[c * 33 + r];
  }
}

// f32 -> bf16 weight conversion, 4-wide
__global__ __launch_bounds__(256) void cvt_bf16(
    const float* __restrict__ src, bf16* __restrict__ dst, int n4)
{
  const int i = blockIdx.x * 256 + threadIdx.x;
  if (i < n4) {
    const float4 v = ((const float4*)src)[i];
    bf16x4 o;
    o[0] = (bf16)v.x; o[1] = (bf16)v.y; o[2] = (bf16)v.z; o[3] = (bf16)v.w;
    ((bf16x4*)dst)[i] = o;
  }
}

extern "C" void kernel_launch(void* const* d_in, const int* in_sizes, int n_in,
                              void* d_out, int out_size, void* d_ws, size_t ws_size,
                              hipStream_t stream)
{
  const float* x_in  = (const float*)d_in[0];
  const float* adj   = (const float*)d_in[1];
  const float* wattn = (const float*)d_in[2];
  const float* battn = (const float*)d_in[3];
  const float* w0    = (const float*)d_in[4];
  const float* b0    = (const float*)d_in[5];
  const float* w1    = (const float*)d_in[6];
  const float* b1    = (const float*)d_in[7];
  const float* wf    = (const float*)d_in[8];
  const float* bfin  = (const float*)d_in[9];

  float* out_x    = (float*)d_out;                     // [B,N,D] f32 master
  float* out_attn = out_x + (size_t)B_ * N_ * D_;      // [L,B,N,N]

  // workspace carve-up (bf16 elements)
  bf16* wb = (bf16*)d_ws;                              // 13 * D*D weights
  bf16* xb = wb + 13 * (D_ * D_);                      // [B,N,D] bf16
  bf16* xT = xb + (size_t)B_ * N_ * D_;                // [B,D,N] bf16
  bf16* qb = xT + (size_t)B_ * N_ * D_;                // q, reused as x'
  bf16* Sb = qb + (size_t)B_ * N_ * D_;                // [B,N,N] S; reused as h
  bf16* hb = Sb;                                       // alias (S dead by then)

  const int DD2 = D_ * D_;
  const int Mfull = B_ * N_;  // 32768

  // weights -> bf16 (every launch: same work each call)
  cvt_bf16<<<dim3((L_ * DD2 / 4 + 255) / 256), 256, 0, stream>>>(wattn, wb, L_ * DD2 / 4);
  cvt_bf16<<<dim3((L_ * DD2 / 4 + 255) / 256), 256, 0, stream>>>(w0, wb + 4 * DD2, L_ * DD2 / 4);
  cvt_bf16<<<dim3((L_ * DD2 / 4 + 255) / 256), 256, 0, stream>>>(w1, wb + 8 * DD2, L_ * DD2 / 4);
  cvt_bf16<<<dim3((DD2 / 4 + 255) / 256), 256, 0, stream>>>(wf, wb + 12 * DD2, DD2 / 4);

  init_x<<<dim3(N_ / 32, D_ / 32, B_), 256, 0, stream>>>(x_in, out_x, xb, xT);

  for (int l = 0; l < L_; ++l) {
    // q = x @ Wattn^T + b
    gemm_bt<<<dim3(2, Mfull / 128, 1), 256, 0, stream>>>(
        xb, wb + l * DD2, battn + l * D_, nullptr,
        nullptr, qb, nullptr,
        Mfull, D_, D_, D_, D_, 0, 0, 0, 0);
    // attention: S (normalized) -> out_attn[l], Sb
    attn_kernel<<<dim3(N_ / 16, B_), 256, 0, stream>>>(
        qb, xb, adj, out_attn + (size_t)l * B_ * N_ * N_, Sb);
    // x' = S @ x  (batched; B-operand = xT rows)  -> qb (q is dead)
    gemm_bt<<<dim3(2, N_ / 128, B_), 256, 0, stream>>>(
        Sb, xT, nullptr, nullptr,
        nullptr, qb, nullptr,
        N_, N_, N_, N_, D_,
        (long long)N_ * N_, (long long)D_ * N_, (long long)N_ * D_, 0);
    // h = relu(x' @ W0^T + b0) -> hb (aliases Sb; S dead)
    gemm_bt<<<dim3(2, Mfull / 128, 1), 256, 0, stream>>>(
        qb, wb + (4 + l) * DD2, b0 + l * D_, nullptr,
        nullptr, hb, nullptr,
        Mfull, D_, D_, D_, D_, 0, 0, 0, 1);
    // x = relu(h @ W1^T + b1) + x0 -> out_x (f32), xb, xT
    gemm_bt<<<dim3(2, Mfull / 128, 1), 256, 0, stream>>>(
        hb, wb + (8 + l) * DD2, b1 + l * D_, out_x,
        out_x, xb, xT,
        Mfull, D_, D_, D_, D_, 0, 0, 0, 1);
  }
  // final: out = x @ Wf^T + bf
  gemm_bt<<<dim3(2, Mfull / 128, 1), 256, 0, stream>>>(
      xb, wb + 12 * DD2, bfin, nullptr,
      out_x, nullptr, nullptr,
      Mfull, D_, D_, D_, D_, 0, 0, 0, 0);
}